// Round 5
// baseline (171.174 us; speedup 1.0000x reference)
//
#include <hip/hip_runtime.h>

#define NBINS 256
#define ROWS 96                    // b*c = 32*3
#define ROW_N (512 * 512)          // 262144 elements per row
#define BPR 16                     // blocks per row
#define CHUNK (ROW_N / BPR)        // 16384 elements per block
#define BLOCK 256
#define WAVES (BLOCK / 64)
#define BIN_W 0.99609375f          // (255-0)/256, exactly representable
#define RECIP_W 1.00392156862745098f  // fl(256/255)

#define PART_WORDS ((size_t)ROWS * BPR * NBINS)       // 393216 u32 partials
#define CTR_OFF PART_WORDS                            // ctr[ROWS]
#define BASE_OFF (PART_WORDS + 128)                   // base[ROWS], own line
#define WS_NEEDED ((BASE_OFF + ROWS) * sizeof(unsigned int))

// ---- binning shared by both paths: exact floor(fv / BIN_W) without v_div ----
__device__ __forceinline__ int bin_of(float fv, bool* valid) {
    float bf = truncf(fv * RECIP_W);      // floor-estimate, |err| <= 1 bin
    float t = bf * BIN_W;                 // exact (b*255 < 2^17)
    int b = (int)bf + (int)((t + BIN_W) <= fv) - (int)(t > fv);  // exact fixup
    b = b > NBINS - 1 ? NBINS - 1 : b;    // also maps fv==255 -> 255
    *valid = (fv >= 0.0f) && (fv <= 255.0f);   // NaN -> false
    return b;
}

// ======== fused path: per-wave LDS hist + per-row last-block finisher ========
__global__ __launch_bounds__(BLOCK) void nh_hist_fused(
        const float* __restrict__ x, unsigned int* __restrict__ ws,
        float* __restrict__ out) {
    __shared__ unsigned int lh[WAVES][NBINS + 1];   // +1 = trash for invalid
    __shared__ unsigned int s_old, s_base;
    const int tid = threadIdx.x;
    const int wave = tid >> 6;

    #pragma unroll
    for (int i = tid; i < WAVES * (NBINS + 1); i += BLOCK)
        ((unsigned int*)lh)[i] = 0u;
    __syncthreads();

    const int row = blockIdx.y;
    const float4* __restrict__ p =
        (const float4*)(x + (size_t)row * ROW_N + (size_t)blockIdx.x * CHUNK);

    #pragma unroll 4
    for (int i = tid; i < CHUNK / 4; i += BLOCK) {
        float4 v = p[i];
        float f[4] = {v.x, v.y, v.z, v.w};
        #pragma unroll
        for (int k = 0; k < 4; ++k) {
            bool valid;
            int b = bin_of(f[k], &valid);
            atomicAdd(&lh[wave][valid ? b : NBINS], 1u);
        }
    }
    __syncthreads();

    // cross-wave reduce; non-atomic coalesced partial store
    unsigned int total = 0;
    #pragma unroll
    for (int w = 0; w < WAVES; ++w) total += lh[w][tid];
    ws[((size_t)row * BPR + blockIdx.x) * NBINS + tid] = total;

    // release: make partial visible device-wide, then take a ticket
    __threadfence();
    if (tid == 0) {
        s_old = atomicAdd(&ws[CTR_OFF + row], 1u);
        s_base = __hip_atomic_load(&ws[BASE_OFF + row], __ATOMIC_RELAXED,
                                   __HIP_MEMORY_SCOPE_AGENT);
    }
    __syncthreads();

    // exactly one block per row sees all BPR partials written
    if (s_old - s_base == BPR - 1) {
        __threadfence();   // acquire: invalidate stale lines
        unsigned int s = 0;
        #pragma unroll
        for (int j = 0; j < BPR; ++j)
            s += ws[((size_t)row * BPR + j) * NBINS + tid];
        // exact: s <= 2^18, scale by 2^-18 -> bit-identical to reference
        out[row * NBINS + tid] = (float)s * (1.0f / ROW_N);
        if (tid == 0)   // advance epoch for the next call (self-maintaining)
            __hip_atomic_store(&ws[BASE_OFF + row], s_old + 1,
                               __ATOMIC_RELEASE, __HIP_MEMORY_SCOPE_AGENT);
    }
}

// ======== fallback (ws too small): zero + LDS hist + float atomics ========
__global__ void nh_zero_out(float* __restrict__ out) {
    out[blockIdx.x * NBINS + threadIdx.x] = 0.0f;
}

__global__ __launch_bounds__(BLOCK) void nh_hist_atomic(
        const float* __restrict__ x, float* __restrict__ out) {
    __shared__ unsigned int lh[WAVES][NBINS + 1];
    const int tid = threadIdx.x;
    const int wave = tid >> 6;
    #pragma unroll
    for (int i = tid; i < WAVES * (NBINS + 1); i += BLOCK)
        ((unsigned int*)lh)[i] = 0u;
    __syncthreads();
    const int row = blockIdx.y;
    const float4* __restrict__ p =
        (const float4*)(x + (size_t)row * ROW_N + (size_t)blockIdx.x * CHUNK);
    #pragma unroll 4
    for (int i = tid; i < CHUNK / 4; i += BLOCK) {
        float4 v = p[i];
        float f[4] = {v.x, v.y, v.z, v.w};
        #pragma unroll
        for (int k = 0; k < 4; ++k) {
            bool valid;
            int b = bin_of(f[k], &valid);
            atomicAdd(&lh[wave][valid ? b : NBINS], 1u);
        }
    }
    __syncthreads();
    unsigned int total = 0;
    #pragma unroll
    for (int w = 0; w < WAVES; ++w) total += lh[w][tid];
    atomicAdd(&out[row * NBINS + tid], (float)total * (1.0f / ROW_N));
}

extern "C" void kernel_launch(void* const* d_in, const int* in_sizes, int n_in,
                              void* d_out, int out_size, void* d_ws, size_t ws_size,
                              hipStream_t stream) {
    const float* x = (const float*)d_in[0];
    float* out = (float*)d_out;
    unsigned int* ws = (unsigned int*)d_ws;

    dim3 grid(BPR, ROWS);
    if (ws_size >= WS_NEEDED) {
        nh_hist_fused<<<grid, BLOCK, 0, stream>>>(x, ws, out);
    } else {
        nh_zero_out<<<ROWS, NBINS, 0, stream>>>(out);
        nh_hist_atomic<<<grid, BLOCK, 0, stream>>>(x, out);
    }
}

// Round 6
// 22.805 us; speedup vs baseline: 7.5059x; 7.5059x over previous
//
#include <hip/hip_runtime.h>

#define NBINS 256
#define ROWS 96                    // b*c = 32*3
#define ROW_N (512 * 512)          // 262144 elements per row
#define BPR 8                      // blocks per row
#define CHUNK (ROW_N / BPR)        // 32768 elements per block
#define BLOCK 512
#define WAVES (BLOCK / 64)         // 8
#define BIN_W 0.99609375f          // (255-0)/256, exactly representable
#define RECIP_W 1.00392156862745098f  // fl(256/255)
#define WS_NEEDED ((size_t)ROWS * BPR * NBINS * sizeof(unsigned int))

// exact floor(fv / BIN_W) without v_div: multiply-estimate + exact fixup.
// bf*BIN_W and (bf+1)*BIN_W are EXACT in fp32 (b <= 256 -> b*255 < 2^17),
// so the compares compute the true floor. Verified bit-exact (R3/R4 absmax=0).
__device__ __forceinline__ int bin_of(float fv, bool* valid) {
    float bf = truncf(fv * RECIP_W);
    float t = bf * BIN_W;
    int b = (int)bf + (int)((t + BIN_W) <= fv) - (int)(t > fv);
    b = b > NBINS - 1 ? NBINS - 1 : b;    // also maps fv==255 -> 255
    *valid = (fv >= 0.0f) && (fv <= 255.0f);   // NaN -> false
    return b;
}

template <bool USE_WS>
__global__ __launch_bounds__(BLOCK) void nh_hist(const float* __restrict__ x,
                                                 unsigned int* __restrict__ ws,
                                                 float* __restrict__ out) {
    __shared__ unsigned int lh[WAVES][NBINS + 1];   // +1 = trash for invalid
    const int tid = threadIdx.x;
    const int wave = tid >> 6;

    #pragma unroll
    for (int i = tid; i < WAVES * (NBINS + 1); i += BLOCK)
        ((unsigned int*)lh)[i] = 0u;
    __syncthreads();

    const int row = blockIdx.y;
    const float4* __restrict__ p =
        (const float4*)(x + (size_t)row * ROW_N + (size_t)blockIdx.x * CHUNK);

    // 16 float4 per thread; unroll 8 keeps 8 dwordx4 loads in flight ahead
    // of the dependent DS-atomic chains.
    #pragma unroll 8
    for (int i = tid; i < CHUNK / 4; i += BLOCK) {
        float4 v = p[i];
        float f[4] = {v.x, v.y, v.z, v.w};
        #pragma unroll
        for (int k = 0; k < 4; ++k) {
            bool valid;
            int b = bin_of(f[k], &valid);
            atomicAdd(&lh[wave][valid ? b : NBINS], 1u);
        }
    }
    __syncthreads();

    // cross-wave reduce (lh[w][tid] stride 257 words -> conflict-free)
    if (tid < NBINS) {
        unsigned int total = 0;
        #pragma unroll
        for (int w = 0; w < WAVES; ++w) total += lh[w][tid];

        if (USE_WS) {
            // non-atomic coalesced partial; block owns its slot
            ws[((size_t)row * BPR + blockIdx.x) * NBINS + tid] = total;
        } else {
            // fallback: float atomic into pre-zeroed out (exact: multiples
            // of 2^-18, k <= 2^18 < 2^24 -> order-independent)
            atomicAdd(&out[row * NBINS + tid], (float)total * (1.0f / ROW_N));
        }
    }
}

__global__ void nh_reduce(const unsigned int* __restrict__ ws,
                          float* __restrict__ out) {
    const int row = blockIdx.x;
    const int bin = threadIdx.x;
    unsigned int s = 0;
    #pragma unroll
    for (int j = 0; j < BPR; ++j)
        s += ws[((size_t)row * BPR + j) * NBINS + bin];
    out[row * NBINS + bin] = (float)s * (1.0f / ROW_N);  // exact
}

__global__ void nh_zero_out(float* __restrict__ out) {
    out[blockIdx.x * NBINS + threadIdx.x] = 0.0f;
}

extern "C" void kernel_launch(void* const* d_in, const int* in_sizes, int n_in,
                              void* d_out, int out_size, void* d_ws, size_t ws_size,
                              hipStream_t stream) {
    const float* x = (const float*)d_in[0];
    float* out = (float*)d_out;
    unsigned int* ws = (unsigned int*)d_ws;

    dim3 grid(BPR, ROWS);
    if (ws_size >= WS_NEEDED) {
        nh_hist<true><<<grid, BLOCK, 0, stream>>>(x, ws, out);
        nh_reduce<<<ROWS, NBINS, 0, stream>>>(ws, out);
    } else {
        nh_zero_out<<<ROWS, NBINS, 0, stream>>>(out);
        nh_hist<false><<<grid, BLOCK, 0, stream>>>(x, ws, out);
    }
}